// Round 11
// baseline (394.741 us; speedup 1.0000x reference)
//
#include <hip/hip_runtime.h>
#include <hip/hip_bf16.h>
#include <cstdint>

// Problem shape (Transducer joint network):
//   enc (4,160,640) fp32, dec (4,80,640) fp32, W1 (1280,640), b1 (640),
//   W2 (640,1024), b2 (1024).  out = (4,160,80,1024) fp32 = 52.4M floats.
#define D_    640
#define V_    1024
#define M_    51200

typedef __bf16 bf16x8 __attribute__((ext_vector_type(8)));
typedef float floatx4 __attribute__((ext_vector_type(4)));

__device__ __forceinline__ void g2l16(const void* g, void* l) {
    __builtin_amdgcn_global_load_lds((const __attribute__((address_space(1))) void*)g,
                                     (__attribute__((address_space(3))) void*)l,
                                     16, 0, 0);
}

__device__ __forceinline__ float fast_tanh(float x) {
    float e = __builtin_amdgcn_exp2f(x * 2.8853900817779268f); // 2*log2(e)
    return 1.0f - 2.0f * __builtin_amdgcn_rcpf(e + 1.0f);
}

// ---------------------------------------------------------------------------
// Kernel 1: fp32 projections -> d_ws. 64x64 tiles, 4x4/thread.
// b1 FOLDED into encp (k-only bias): hidden = tanh((e+b1) + d).
// ---------------------------------------------------------------------------
__global__ __launch_bounds__(256) void proj_kernel(
    const float* __restrict__ enc, const float* __restrict__ dec,
    const float* __restrict__ W1, const float* __restrict__ b1,
    float* __restrict__ encp, float* __restrict__ decp) {
    __shared__ float As[64][36];
    __shared__ float Ws[32][68];

    const int rt = blockIdx.y;     // 0..14 (10 enc row-tiles, 5 dec row-tiles)
    const int ct = blockIdx.x;     // 0..9
    const bool is_enc = (rt < 10);
    const float* Asrc; const float* Wsrc; float* Cdst;
    if (is_enc) { Asrc = enc + (size_t)rt * 64 * D_;        Wsrc = W1;           Cdst = encp + (size_t)rt * 64 * D_; }
    else        { Asrc = dec + (size_t)(rt - 10) * 64 * D_; Wsrc = W1 + D_ * D_; Cdst = decp + (size_t)(rt - 10) * 64 * D_; }

    const int tid = threadIdx.x;
    const int ar = tid >> 2,  ac = (tid & 3) * 8;
    const int wr2 = tid >> 3, wc2 = (tid & 7) * 8;
    const int tr = tid >> 4,  tc = tid & 15;

    float acc[4][4] = {};
    for (int k0 = 0; k0 < D_; k0 += 32) {
        __syncthreads();
        *(floatx4*)&As[ar][ac]       = *(const floatx4*)&Asrc[(size_t)ar * D_ + k0 + ac];
        *(floatx4*)&As[ar][ac + 4]   = *(const floatx4*)&Asrc[(size_t)ar * D_ + k0 + ac + 4];
        *(floatx4*)&Ws[wr2][wc2]     = *(const floatx4*)&Wsrc[(size_t)(k0 + wr2) * D_ + ct * 64 + wc2];
        *(floatx4*)&Ws[wr2][wc2 + 4] = *(const floatx4*)&Wsrc[(size_t)(k0 + wr2) * D_ + ct * 64 + wc2 + 4];
        __syncthreads();
#pragma unroll
        for (int kk = 0; kk < 32; kk++) {
            floatx4 w = *(const floatx4*)&Ws[kk][tc * 4];
            float a0 = As[tr * 4 + 0][kk], a1 = As[tr * 4 + 1][kk];
            float a2 = As[tr * 4 + 2][kk], a3 = As[tr * 4 + 3][kk];
#pragma unroll
            for (int j = 0; j < 4; j++) {
                acc[0][j] += a0 * w[j]; acc[1][j] += a1 * w[j];
                acc[2][j] += a2 * w[j]; acc[3][j] += a3 * w[j];
            }
        }
    }
    floatx4 bv = {0.f, 0.f, 0.f, 0.f};
    if (is_enc) bv = *(const floatx4*)&b1[ct * 64 + tc * 4];
#pragma unroll
    for (int i = 0; i < 4; i++) {
        floatx4 v = { acc[i][0] + bv[0], acc[i][1] + bv[1],
                      acc[i][2] + bv[2], acc[i][3] + bv[3] };
        *(floatx4*)&Cdst[(size_t)(tr * 4 + i) * D_ + ct * 64 + tc * 4] = v;
    }
}

// ---------------------------------------------------------------------------
// Kernel 2: W2 (640x1024 fp32 KxN) -> W2t (1024x640 bf16 NxK) in d_ws.
// ---------------------------------------------------------------------------
__global__ __launch_bounds__(256) void w2t_kernel(
    const float* __restrict__ W2, __bf16* __restrict__ W2t) {
    __shared__ __bf16 tile[32][33];
    const int vt = blockIdx.x;           // 0..31
    const int kt = blockIdx.y;           // 0..19
    const int tx = threadIdx.x & 31, ty = threadIdx.x >> 5;
#pragma unroll
    for (int i = 0; i < 4; i++)
        tile[ty + i * 8][tx] = (__bf16)W2[(size_t)(kt * 32 + ty + i * 8) * V_ + vt * 32 + tx];
    __syncthreads();
#pragma unroll
    for (int i = 0; i < 4; i++)
        W2t[(size_t)(vt * 32 + ty + i * 8) * D_ + kt * 32 + tx] = tile[tx][ty + i * 8];
}

// ---------------------------------------------------------------------------
// Kernel 3 (fused, FULL-N): C[m0..m0+64][0..1024] = tanh(e'+d) @ W2t^T + b2.
//
// ROUND-11: BN = N = 1024 kills the r5/r6 fused duplication (tanh and ED
// loads were recomputed once per 256-col N-tile = 4x, ~36% of the serial
// budget) while keeping fusion's wins (no H buffer, no hidden kernel).
//   BM=64, BN=1024, BK=32, 512 thr = 8 waves (1M x 8N), wave out 64x128,
//   accT[8][4] = 128 VGPR. LDS: A dbuf 2x4KB @0 + B SINGLE 64KB @8192 =
//   72KB -> 2 blocks/CU (partner hides the per-tile vmcnt drain that the
//   single-buffered B requires — the drain is exactly __syncthreads'
//   semantics, so no inline asm at all).
// Per tile: read 12 frags -> regs; sync (LDS free); stage B(t+1) (8 g2l16)
// || produce A(t+1) (threads<256: 8 elems, tanh once) || 32 MFMAs from
// regs; sync. B traffic = 1 GB L2 total (same as all designs); W2t is a
// 1.25MB broadcast -> L3-friendly. 64B LDS rows use the r9-VERIFIED 2-bit
// involution slot16 ^= (row>>1)&3 on all four paths (derivations in-line;
// all reduce to lane-constants). Swapped-operand MFMA + r9-verified
// dwordx4 epilogue. Accumulation order unchanged (k-ascending) -> same
// absmax.
// ---------------------------------------------------------------------------
__global__ __launch_bounds__(512, 2) void joint_kernel(
    const float* __restrict__ encp, const float* __restrict__ decp,
    const __bf16* __restrict__ W2t, const float* __restrict__ b2,
    float* __restrict__ C) {
    __shared__ __align__(128) char lds[73728];   // A: 2x4KB @0, B: 64KB @8192

    const int bid = blockIdx.x;                  // 800 blocks = 8 XCD x 100
    const int swz = (bid & 7) * 100 + (bid >> 3);
    const int m0 = swz * 64;

    const int tid = threadIdx.x;                 // 0..511
    const int w = tid >> 6, l = tid & 63;        // 8 waves; wave = N-col w
    const int lr = l & 15, lk = l >> 4;

    char* ldsp = (char*)lds;
    char* ldsB = ldsp + 8192;

    // ---- B staging: call c covers rows (c*8+w)*16 + (l>>2), lane slot l&3.
    // (row>>1)&3 = (l>>3)&3 (row base is a multiple of 16) -> source slot
    // pre-swizzle is a lane constant.
    const char* WbL = (const char*)W2t
        + (size_t)(w * 16 + (l >> 2)) * 1280
        + (unsigned)((((l & 3) ^ ((l >> 3) & 3)) * 16));
    const unsigned bdst = (unsigned)(w * 1024 + l * 16);  // + c*8192

    // ---- A produce: threads 0..255; thread owns row pr (0..63), 8 k-elems.
    const int pr = (tid & 255) >> 2;
    const int kq = tid & 3;
    const int R  = m0 + pr;
    const int bt = R / 80;
    const int uu = R - bt * 80;
    const int drw = (bt / 160) * 80 + uu;
    const float* ep = encp + (size_t)bt * D_ + kq * 8;   // b1 already folded
    const float* dp = decp + (size_t)drw * D_ + kq * 8;
    const unsigned pwr = (unsigned)(pr * 64 + (((kq ^ ((pr >> 1) & 3)) * 16)));

    // ---- frag reads: phys slot = lk ^ ((lr>>1)&3) (i*16/j*16/w*128 row
    // offsets are invisible to (row>>1)&3).
    const unsigned px16 = (unsigned)((lk ^ ((lr >> 1) & 3)) * 16);

    // accT[j][i]: j = N sub-tile (8), i = M sub-tile (4) — swapped-operand.
    floatx4 accT[8][4] = {};

#define STAGE_B(T) do { \
    const char* _s = WbL + (size_t)(T) * 64; \
    _Pragma("unroll") for (int c = 0; c < 8; ++c) \
        g2l16(_s + (size_t)c * 163840, ldsB + bdst + c * 8192); \
  } while (0)

#define PRODUCE_A(BUF, T) do { \
    if (tid < 256) { \
      const float* _e = ep + (T) * 32; const float* _d = dp + (T) * 32; \
      floatx4 e0 = *(const floatx4*)_e, e1 = *(const floatx4*)(_e + 4); \
      floatx4 d0 = *(const floatx4*)_d, d1 = *(const floatx4*)(_d + 4); \
      bf16x8 h; \
      _Pragma("unroll") for (int i2 = 0; i2 < 4; ++i2) { \
        h[i2]     = (__bf16)fast_tanh(e0[i2] + d0[i2]); \
        h[i2 + 4] = (__bf16)fast_tanh(e1[i2] + d1[i2]); \
      } \
      *(bf16x8*)(ldsp + (BUF) * 4096 + pwr) = h; \
    } } while (0)

    // ---- prologue ----
    STAGE_B(0);
    PRODUCE_A(0, 0);
    __syncthreads();

#pragma unroll 1
    for (int t = 0; t < 20; ++t) {               // 20 K-tiles of 32
        const int buf = t & 1, nb = buf ^ 1;
        bf16x8 af[4], bfr[8];
#pragma unroll
        for (int i = 0; i < 4; ++i)
            af[i] = *(const bf16x8*)(ldsp + buf * 4096 + (i * 16 + lr) * 64 + px16);
#pragma unroll
        for (int j = 0; j < 8; ++j)
            bfr[j] = *(const bf16x8*)(ldsB + (w * 128 + j * 16 + lr) * 64 + px16);
        __syncthreads();                         // all frags in regs; LDS free
        if (t < 19) {
            STAGE_B(t + 1);                      // overwrite B in place
            PRODUCE_A(nb, t + 1);                // write other A half
        }
#pragma unroll
        for (int j = 0; j < 8; ++j)
#pragma unroll
            for (int i = 0; i < 4; ++i)
                accT[j][i] = __builtin_amdgcn_mfma_f32_16x16x32_bf16(bfr[j], af[i], accT[j][i], 0, 0, 0);
        if (t < 19) __syncthreads();             // drains g2l + ds_writes
    }

    // ---- epilogue (swapped layout, r9-verified): lane&15 = M-row,
    // (lane>>4)*4 + reg = N-col -> 4 regs = 4 consecutive C columns.
#pragma unroll
    for (int j = 0; j < 8; ++j) {
        const int col0 = w * 128 + j * 16 + lk * 4;
        const floatx4 bv = *(const floatx4*)&b2[col0];
#pragma unroll
        for (int i = 0; i < 4; ++i) {
            const int row = m0 + i * 16 + lr;
            floatx4 v = { accT[j][i][0] + bv[0], accT[j][i][1] + bv[1],
                          accT[j][i][2] + bv[2], accT[j][i][3] + bv[3] };
            *(floatx4*)&C[(size_t)row * V_ + col0] = v;
        }
    }
#undef STAGE_B
#undef PRODUCE_A
}

// ---------------------------------------------------------------------------
extern "C" void kernel_launch(void* const* d_in, const int* in_sizes, int n_in,
                              void* d_out, int out_size, void* d_ws, size_t ws_size,
                              hipStream_t stream) {
    const float* enc = (const float*)d_in[0];
    const float* dec = (const float*)d_in[1];
    const float* W1  = (const float*)d_in[2];
    const float* b1  = (const float*)d_in[3];
    const float* W2  = (const float*)d_in[4];
    const float* b2  = (const float*)d_in[5];
    float* out = (float*)d_out;

    // Workspace (d_ws), 3.77 MB:
    char* ws = (char*)d_ws;
    float*  encp = (float*)ws;                         // 640*640*4 (b1 folded)
    float*  decp = (float*)(ws + 1638400);             // 320*640*4
    __bf16* W2t  = (__bf16*)(ws + 1638400 + 819200);   // 1024*640*2

    proj_kernel<<<dim3(10, 15), 256, 0, stream>>>(enc, dec, W1, b1, encp, decp);
    w2t_kernel<<<dim3(32, 20), 256, 0, stream>>>(W2, W2t);
    joint_kernel<<<800, 512, 0, stream>>>(encp, decp, W2t, b2, out);
}

// Round 12
// 347.807 us; speedup vs baseline: 1.1349x; 1.1349x over previous
//
#include <hip/hip_runtime.h>
#include <hip/hip_bf16.h>
#include <cstdint>

// Problem shape (Transducer joint network):
//   enc (4,160,640) fp32, dec (4,80,640) fp32, W1 (1280,640), b1 (640),
//   W2 (640,1024), b2 (1024).  out = (4,160,80,1024) fp32 = 52.4M floats.
#define D_    640
#define V_    1024
#define M_    51200

typedef __bf16 bf16x8 __attribute__((ext_vector_type(8)));
typedef float floatx4 __attribute__((ext_vector_type(4)));

__device__ __forceinline__ void g2l16(const void* g, void* l) {
    __builtin_amdgcn_global_load_lds((const __attribute__((address_space(1))) void*)g,
                                     (__attribute__((address_space(3))) void*)l,
                                     16, 0, 0);
}

__device__ __forceinline__ float fast_tanh(float x) {
    float e = __builtin_amdgcn_exp2f(x * 2.8853900817779268f); // 2*log2(e)
    return 1.0f - 2.0f * __builtin_amdgcn_rcpf(e + 1.0f);
}

// ---------------------------------------------------------------------------
// Kernel 1: fp32 projections -> d_ws. 64x64 tiles, 4x4/thread.
// b1 FOLDED into encp (k-only bias): hidden = tanh((e+b1) + d).
// ---------------------------------------------------------------------------
__global__ __launch_bounds__(256) void proj_kernel(
    const float* __restrict__ enc, const float* __restrict__ dec,
    const float* __restrict__ W1, const float* __restrict__ b1,
    float* __restrict__ encp, float* __restrict__ decp) {
    __shared__ float As[64][36];
    __shared__ float Ws[32][68];

    const int rt = blockIdx.y;     // 0..14 (10 enc row-tiles, 5 dec row-tiles)
    const int ct = blockIdx.x;     // 0..9
    const bool is_enc = (rt < 10);
    const float* Asrc; const float* Wsrc; float* Cdst;
    if (is_enc) { Asrc = enc + (size_t)rt * 64 * D_;        Wsrc = W1;           Cdst = encp + (size_t)rt * 64 * D_; }
    else        { Asrc = dec + (size_t)(rt - 10) * 64 * D_; Wsrc = W1 + D_ * D_; Cdst = decp + (size_t)(rt - 10) * 64 * D_; }

    const int tid = threadIdx.x;
    const int ar = tid >> 2,  ac = (tid & 3) * 8;
    const int wr2 = tid >> 3, wc2 = (tid & 7) * 8;
    const int tr = tid >> 4,  tc = tid & 15;

    float acc[4][4] = {};
    for (int k0 = 0; k0 < D_; k0 += 32) {
        __syncthreads();
        *(floatx4*)&As[ar][ac]       = *(const floatx4*)&Asrc[(size_t)ar * D_ + k0 + ac];
        *(floatx4*)&As[ar][ac + 4]   = *(const floatx4*)&Asrc[(size_t)ar * D_ + k0 + ac + 4];
        *(floatx4*)&Ws[wr2][wc2]     = *(const floatx4*)&Wsrc[(size_t)(k0 + wr2) * D_ + ct * 64 + wc2];
        *(floatx4*)&Ws[wr2][wc2 + 4] = *(const floatx4*)&Wsrc[(size_t)(k0 + wr2) * D_ + ct * 64 + wc2 + 4];
        __syncthreads();
#pragma unroll
        for (int kk = 0; kk < 32; kk++) {
            floatx4 w = *(const floatx4*)&Ws[kk][tc * 4];
            float a0 = As[tr * 4 + 0][kk], a1 = As[tr * 4 + 1][kk];
            float a2 = As[tr * 4 + 2][kk], a3 = As[tr * 4 + 3][kk];
#pragma unroll
            for (int j = 0; j < 4; j++) {
                acc[0][j] += a0 * w[j]; acc[1][j] += a1 * w[j];
                acc[2][j] += a2 * w[j]; acc[3][j] += a3 * w[j];
            }
        }
    }
    floatx4 bv = {0.f, 0.f, 0.f, 0.f};
    if (is_enc) bv = *(const floatx4*)&b1[ct * 64 + tc * 4];
#pragma unroll
    for (int i = 0; i < 4; i++) {
        floatx4 v = { acc[i][0] + bv[0], acc[i][1] + bv[1],
                      acc[i][2] + bv[2], acc[i][3] + bv[3] };
        *(floatx4*)&Cdst[(size_t)(tr * 4 + i) * D_ + ct * 64 + tc * 4] = v;
    }
}

// ---------------------------------------------------------------------------
// Kernel 2: W2 (640x1024 fp32 KxN) -> W2t (1024x640 bf16 NxK) in d_ws.
// ---------------------------------------------------------------------------
__global__ __launch_bounds__(256) void w2t_kernel(
    const float* __restrict__ W2, __bf16* __restrict__ W2t) {
    __shared__ __bf16 tile[32][33];
    const int vt = blockIdx.x;           // 0..31
    const int kt = blockIdx.y;           // 0..19
    const int tx = threadIdx.x & 31, ty = threadIdx.x >> 5;
#pragma unroll
    for (int i = 0; i < 4; i++)
        tile[ty + i * 8][tx] = (__bf16)W2[(size_t)(kt * 32 + ty + i * 8) * V_ + vt * 32 + tx];
    __syncthreads();
#pragma unroll
    for (int i = 0; i < 4; i++)
        W2t[(size_t)(vt * 32 + ty + i * 8) * D_ + kt * 32 + tx] = tile[tx][ty + i * 8];
}

// ---------------------------------------------------------------------------
// Kernel 3: hidden[m][h] = tanh(encp'[bt][h] + decp[b*80+u][h]) -> bf16.
// tanh once per element (fused variants re-computed it 4x — r8/r11 lesson).
// ---------------------------------------------------------------------------
__global__ __launch_bounds__(256) void hidden_kernel(
    const float* __restrict__ encp, const float* __restrict__ decp,
    __bf16* __restrict__ H) {
    const unsigned g = blockIdx.x * 256u + threadIdx.x;  // 0..4,095,999
    const unsigned row = g / 80u;
    const unsigned hg  = g % 80u;
    const unsigned u   = row % 80u;
    const unsigned bt  = row / 80u;
    const unsigned b   = bt / 160u;

    const float* ep = encp + (size_t)bt * D_ + hg * 8;
    const float* dp = decp + (size_t)(b * 80u + u) * D_ + hg * 8;

    floatx4 e0 = *(const floatx4*)ep, e1 = *(const floatx4*)(ep + 4);
    floatx4 d0 = *(const floatx4*)dp, d1 = *(const floatx4*)(dp + 4);

    bf16x8 hv;
#pragma unroll
    for (int i = 0; i < 4; i++) hv[i]     = (__bf16)fast_tanh(e0[i] + d0[i]);
#pragma unroll
    for (int i = 0; i < 4; i++) hv[i + 4] = (__bf16)fast_tanh(e1[i] + d1[i]);

    *(bf16x8*)(H + (size_t)g * 8) = hv;
}

// ---------------------------------------------------------------------------
// Kernel 4: C[51200x1024] = H @ W2t^T + b2.  256x256 8-phase schedule.
//
// ROUND-12 FIXES to the r1/r10 8-phase gemm:
// (a) __launch_bounds__(512, 1): the old (512,2) capped VGPRs at 128
//     (r11 evidence: VGPR_Count=108 with a 128-reg accumulator => acc was
//     SPILLING in every 8-phase round). 128KB LDS forces 1 block/CU anyway;
//     (512,1) restores the 256-reg cap. acc 128 + 2x frag sets 96 + addr
//     fits without spill.
// (b) Prefetch-RD under MFMA + full Gray reuse with TWO af/bg register
//     sets: phase body = [STG; vmcnt?; BAR; RD(frags for a later phase);
//     MFMA(this phase)]. The LDS port services reads DURING the MFMA
//     window; 24 frag-reads/tile (vs 48 in r1, 32 in r10) => port (576
//     cyc avg/phase) < MFMA (621) => MFMA-bound phases.
// Set rotation (audited, no use/overwrite conflict):
//   P0: RD afY<-b0.A1 ; MM(afX,bgX)(0,0)   P4: RD afX<-b1.A1 ; MM(afY,bgX)(0,0)
//   P1: RD bgY<-b0.B1 ; MM(afY,bgX)(1,0)   P5: RD bgY<-b1.B1 ; MM(afX,bgX)(1,0)
//   P2:              ; MM(afY,bgY)(1,1)   P6:              ; MM(afX,bgY)(1,1)
//   P3: RD afY,bgX<-b1.{A0,B0} ; MM(afX,bgY)(0,1)
//                                          P7: RD afX,bgX<-b0.{A0,B0} ; MM(afY,bgY)(0,1)
// Staging + vmcnt positions are IDENTICAL to r10 (which passed). Coverage
// re-audited in vmem-OPS (each STG = 2 ops): VM6 => <=3 slices outstanding;
// at P3 all slices through buf1.A0 complete (covers P3-P5 reads); at P7
// all of next buf0 complete (covers P7 + next P0/P1 reads). Per-quadrant
// K-accumulation order unchanged => bit-identical output.
// ---------------------------------------------------------------------------
#define VM6  asm volatile("s_waitcnt vmcnt(6)" ::: "memory")
#define VM0  asm volatile("s_waitcnt vmcnt(0)" ::: "memory")
#define BAR  __builtin_amdgcn_s_barrier()
#define SCB  __builtin_amdgcn_sched_barrier(0)

#define STG_A(BUF, S, TL) do { \
    g2l16(Hb + (unsigned)((S)*163840 + (TL)*128) + agl,         ldsp + (BUF)*32768 + (S)*16384 + stl); \
    g2l16(Hb + (unsigned)((S)*163840 + (TL)*128 + 10240) + agl, ldsp + (BUF)*32768 + (S)*16384 + stl + 1024); \
  } while (0)
#define STG_B(BUF, S, TL) do { \
    g2l16(Wb + (unsigned)((S)*163840 + (TL)*128) + agl,         ldsp + 65536 + (BUF)*32768 + (S)*16384 + stl); \
    g2l16(Wb + (unsigned)((S)*163840 + (TL)*128 + 10240) + agl, ldsp + 65536 + (BUF)*32768 + (S)*16384 + stl + 1024); \
  } while (0)

#define RD_A2(D0, D1, ABUF, QM) do { \
    _Pragma("unroll") for (int ii = 0; ii < 4; ++ii) { \
      D0[ii] = *(const bf16x8*)(ldsp + (ABUF)*32768 + (QM)*16384 + ii*2048 + aRowB + sx0); \
      D1[ii] = *(const bf16x8*)(ldsp + (ABUF)*32768 + (QM)*16384 + ii*2048 + aRowB + sx1); \
    } } while (0)
#define RD_B2(G0, G1, BBUF, QN) do { \
    _Pragma("unroll") for (int jj = 0; jj < 2; ++jj) { \
      G0[jj] = *(const bf16x8*)(ldsp + 65536 + (BBUF)*32768 + (QN)*16384 + jj*2048 + bRowB + sx0); \
      G1[jj] = *(const bf16x8*)(ldsp + 65536 + (BBUF)*32768 + (QN)*16384 + jj*2048 + bRowB + sx1); \
    } } while (0)
#define MM2(A0, A1, G0, G1, QM, QN) do { \
    __builtin_amdgcn_s_setprio(1); \
    _Pragma("unroll") for (int ii = 0; ii < 4; ++ii) \
      _Pragma("unroll") for (int jj = 0; jj < 2; ++jj) { \
        acc[(QM)*4+ii][(QN)*2+jj] = __builtin_amdgcn_mfma_f32_16x16x32_bf16(A0[ii], G0[jj], acc[(QM)*4+ii][(QN)*2+jj], 0, 0, 0); \
        acc[(QM)*4+ii][(QN)*2+jj] = __builtin_amdgcn_mfma_f32_16x16x32_bf16(A1[ii], G1[jj], acc[(QM)*4+ii][(QN)*2+jj], 0, 0, 0); \
      } \
    __builtin_amdgcn_s_setprio(0); \
  } while (0)

__global__ __launch_bounds__(512, 1) void gemm_kernel(
    const __bf16* __restrict__ H, const __bf16* __restrict__ W2t,
    const float* __restrict__ b2, float* __restrict__ C) {
    __shared__ __align__(128) char lds[131072];   // A: [0,64K), B: [64K,128K)

    // XCD swizzle: 800 blocks, 8 XCDs, 100 contiguous per XCD (r1-verified).
    const int bid = blockIdx.x;
    const int swz = (bid & 7) * 100 + (bid >> 3);
    const int mt = swz >> 2, nt = swz & 3;        // 200 M-tiles x 4 N-tiles
    const int m0 = mt * 256, n0 = nt * 256;

    const int tid = threadIdx.x;
    const int w = tid >> 6, l = tid & 63;
    const int wr = w >> 2, wc = w & 3;            // 2 x 4 wave grid
    const int lrow = l & 15, lk = l >> 4, l7 = l & 7, lhi = l >> 3;

    // staging: pre-swizzled global source, linear LDS dest (r1-verified).
    const unsigned swzb = (unsigned)(((l & 7) ^ lhi) * 16);
    const unsigned agl  = (unsigned)((w * 16 + lhi) * 1280) + swzb;
    const unsigned stl  = (unsigned)(w * 2048 + l * 16);

    const char* Hb = (const char*)H   + (size_t)m0 * 1280;
    const char* Wb = (const char*)W2t + (size_t)n0 * 1280;
    char* ldsp = (char*)lds;

    // ds_read constants (same XOR involution as staging).
    const unsigned aRowB = (unsigned)((wr * 64 + lrow) * 128);
    const unsigned bRowB = (unsigned)(wc * 4096 + lrow * 128);
    const unsigned sx0 = (unsigned)(((0 + lk) ^ l7) * 16);
    const unsigned sx1 = (unsigned)(((4 + lk) ^ l7) * 16);

    floatx4 acc[8][4] = {};
    bf16x8 afX0[4], afX1[4], afY0[4], afY1[4];
    bf16x8 bgX0[2], bgX1[2], bgY0[2], bgY1[2];

    // ---- prologue: t0 {A0,B0,A1,B1} + t1 {B0,A1,B1} = 7 slices (14 ops);
    // VM6 -> <=3 slices outstanding -> all of tile 0 complete. Pre-load the
    // first phase's fragments.
    STG_A(0, 0, 0); STG_B(0, 0, 0); STG_A(0, 1, 0); STG_B(0, 1, 0);
    STG_B(1, 0, 1); STG_A(1, 1, 1); STG_B(1, 1, 1);
    VM6; BAR; SCB;
    RD_A2(afX0, afX1, 0, 0); RD_B2(bgX0, bgX1, 0, 0);

#pragma unroll 1
    for (int it = 0; it < 5; ++it) {              // 10 K-tiles, 2 per iter
        const int t1 = 2 * it + 1, t2 = 2 * it + 2, t3 = 2 * it + 3;
        const bool g = (it < 4);

        // ---- group 0: buf0 (tile 2it) ----
        // P0
        STG_A(1, 0, t1);
        BAR; SCB;
        RD_A2(afY0, afY1, 0, 1);
        MM2(afX0, afX1, bgX0, bgX1, 0, 0);
        BAR; SCB;
        // P1
        if (g) STG_B(0, 0, t2);
        BAR; SCB;
        RD_B2(bgY0, bgY1, 0, 1);
        MM2(afY0, afY1, bgX0, bgX1, 1, 0);
        BAR; SCB;
        // P2
        if (g) STG_A(0, 1, t2);
        BAR; SCB;
        MM2(afY0, afY1, bgY0, bgY1, 1, 1);
        BAR; SCB;
        // P3
        if (g) STG_B(0, 1, t2);
        if (it == 4) { VM0; } else { VM6; }
        BAR; SCB;
        RD_A2(afY0, afY1, 1, 0);      // next tile (2it+1) af(0)
        RD_B2(bgX0, bgX1, 1, 0);      // next tile bg(0)
        MM2(afX0, afX1, bgY0, bgY1, 0, 1);
        BAR; SCB;

        // ---- group 1: buf1 (tile 2it+1) ----
        // P4
        if (g) STG_A(0, 0, t2);
        BAR; SCB;
        RD_A2(afX0, afX1, 1, 1);
        MM2(afY0, afY1, bgX0, bgX1, 0, 0);
        BAR; SCB;
        // P5
        if (g) STG_B(1, 0, t3);
        BAR; SCB;
        RD_B2(bgY0, bgY1, 1, 1);
        MM2(afX0, afX1, bgX0, bgX1, 1, 0);
        BAR; SCB;
        // P6
        if (g) STG_A(1, 1, t3);
        BAR; SCB;
        MM2(afX0, afX1, bgY0, bgY1, 1, 1);
        BAR; SCB;
        // P7
        if (g) STG_B(1, 1, t3);
        if (g) { VM6; }
        BAR; SCB;
        if (g) { RD_A2(afX0, afX1, 0, 0); RD_B2(bgX0, bgX1, 0, 0); }
        MM2(afY0, afY1, bgY0, bgY1, 0, 1);
        BAR; SCB;
    }

    // ---- epilogue (r1-verified): col = lane&15 within 16-col frag ----
#pragma unroll
    for (int j = 0; j < 4; ++j) {
        const int col = n0 + (j >> 1) * 128 + wc * 32 + (j & 1) * 16 + lrow;
        const float bj = b2[col];
#pragma unroll
        for (int i = 0; i < 8; ++i) {
            const int row = m0 + (i >> 2) * 128 + wr * 64 + (i & 3) * 16 + lk * 4;
            float* Cp = C + (size_t)row * V_ + col;
#pragma unroll
            for (int rg = 0; rg < 4; ++rg)
                Cp[(size_t)rg * V_] = acc[i][j][rg] + bj;
        }
    }
}

// ---------------------------------------------------------------------------
extern "C" void kernel_launch(void* const* d_in, const int* in_sizes, int n_in,
                              void* d_out, int out_size, void* d_ws, size_t ws_size,
                              hipStream_t stream) {
    const float* enc = (const float*)d_in[0];
    const float* dec = (const float*)d_in[1];
    const float* W1  = (const float*)d_in[2];
    const float* b1  = (const float*)d_in[3];
    const float* W2  = (const float*)d_in[4];
    const float* b2  = (const float*)d_in[5];
    float* out = (float*)d_out;

    // Workspace (d_ws), ~69.3 MB:
    char* ws = (char*)d_ws;
    float*  encp = (float*)ws;                                   // 640*640*4   (b1 folded)
    float*  decp = (float*)(ws + 1638400);                       // 320*640*4
    __bf16* W2t  = (__bf16*)(ws + 1638400 + 819200);             // 1024*640*2
    __bf16* Hbuf = (__bf16*)(ws + 1638400 + 819200 + 1310720);   // 51200*640*2

    proj_kernel<<<dim3(10, 15), 256, 0, stream>>>(enc, dec, W1, b1, encp, decp);
    w2t_kernel<<<dim3(32, 20), 256, 0, stream>>>(W2, W2t);
    hidden_kernel<<<16000, 256, 0, stream>>>(encp, decp, Hbuf);
    gemm_kernel<<<800, 512, 0, stream>>>(Hbuf, W2t, b2, out);
}

// Round 13
// 339.648 us; speedup vs baseline: 1.1622x; 1.0240x over previous
//
#include <hip/hip_runtime.h>
#include <hip/hip_bf16.h>
#include <cstdint>

// Problem shape (Transducer joint network):
//   enc (4,160,640) fp32, dec (4,80,640) fp32, W1 (1280,640), b1 (640),
//   W2 (640,1024), b2 (1024).  out = (4,160,80,1024) fp32 = 52.4M floats.
#define D_    640
#define V_    1024
#define M_    51200

typedef __bf16 bf16x8 __attribute__((ext_vector_type(8)));
typedef float floatx4 __attribute__((ext_vector_type(4)));

__device__ __forceinline__ void g2l16(const void* g, void* l) {
    __builtin_amdgcn_global_load_lds((const __attribute__((address_space(1))) void*)g,
                                     (__attribute__((address_space(3))) void*)l,
                                     16, 0, 0);
}

__device__ __forceinline__ float fast_tanh(float x) {
    float e = __builtin_amdgcn_exp2f(x * 2.8853900817779268f); // 2*log2(e)
    return 1.0f - 2.0f * __builtin_amdgcn_rcpf(e + 1.0f);
}

// ---------------------------------------------------------------------------
// Kernel 1 (merged prep): blocks 0..149 = fp32 projections (b1 folded into
// encp); blocks 150..789 = W2 -> W2t transpose+bf16. Merging overlaps the
// two independent kernels' tails and saves one launch.
// ---------------------------------------------------------------------------
__global__ __launch_bounds__(256) void prep_kernel(
    const float* __restrict__ enc, const float* __restrict__ dec,
    const float* __restrict__ W1, const float* __restrict__ b1,
    const float* __restrict__ W2,
    float* __restrict__ encp, float* __restrict__ decp,
    __bf16* __restrict__ W2t) {
    __shared__ float As[64][36];
    __shared__ float Ws[32][68];
    __shared__ __bf16 tile[32][33];

    const int bid = blockIdx.x;
    const int tid = threadIdx.x;

    if (bid < 150) {
        // ---- proj: 64x64 C-tiles, 4x4/thread ----
        const int rt = bid / 10;       // 0..14
        const int ct = bid % 10;       // 0..9
        const bool is_enc = (rt < 10);
        const float* Asrc; const float* Wsrc; float* Cdst;
        if (is_enc) { Asrc = enc + (size_t)rt * 64 * D_;        Wsrc = W1;           Cdst = encp + (size_t)rt * 64 * D_; }
        else        { Asrc = dec + (size_t)(rt - 10) * 64 * D_; Wsrc = W1 + D_ * D_; Cdst = decp + (size_t)(rt - 10) * 64 * D_; }

        const int ar = tid >> 2,  ac = (tid & 3) * 8;
        const int wr2 = tid >> 3, wc2 = (tid & 7) * 8;
        const int tr = tid >> 4,  tc = tid & 15;

        float acc[4][4] = {};
        for (int k0 = 0; k0 < D_; k0 += 32) {
            __syncthreads();
            *(floatx4*)&As[ar][ac]       = *(const floatx4*)&Asrc[(size_t)ar * D_ + k0 + ac];
            *(floatx4*)&As[ar][ac + 4]   = *(const floatx4*)&Asrc[(size_t)ar * D_ + k0 + ac + 4];
            *(floatx4*)&Ws[wr2][wc2]     = *(const floatx4*)&Wsrc[(size_t)(k0 + wr2) * D_ + ct * 64 + wc2];
            *(floatx4*)&Ws[wr2][wc2 + 4] = *(const floatx4*)&Wsrc[(size_t)(k0 + wr2) * D_ + ct * 64 + wc2 + 4];
            __syncthreads();
#pragma unroll
            for (int kk = 0; kk < 32; kk++) {
                floatx4 wv = *(const floatx4*)&Ws[kk][tc * 4];
                float a0 = As[tr * 4 + 0][kk], a1 = As[tr * 4 + 1][kk];
                float a2 = As[tr * 4 + 2][kk], a3 = As[tr * 4 + 3][kk];
#pragma unroll
                for (int j = 0; j < 4; j++) {
                    acc[0][j] += a0 * wv[j]; acc[1][j] += a1 * wv[j];
                    acc[2][j] += a2 * wv[j]; acc[3][j] += a3 * wv[j];
                }
            }
        }
        floatx4 bv = {0.f, 0.f, 0.f, 0.f};
        if (is_enc) bv = *(const floatx4*)&b1[ct * 64 + tc * 4];
#pragma unroll
        for (int i = 0; i < 4; i++) {
            floatx4 v = { acc[i][0] + bv[0], acc[i][1] + bv[1],
                          acc[i][2] + bv[2], acc[i][3] + bv[3] };
            *(floatx4*)&Cdst[(size_t)(tr * 4 + i) * D_ + ct * 64 + tc * 4] = v;
        }
    } else {
        // ---- w2t: W2 (640x1024 KxN) -> W2t (1024x640 NxK bf16) ----
        const int idx = bid - 150;
        const int vt = idx & 31;       // 0..31
        const int kt = idx >> 5;       // 0..19
        const int tx = tid & 31, ty = tid >> 5;
#pragma unroll
        for (int i = 0; i < 4; i++)
            tile[ty + i * 8][tx] = (__bf16)W2[(size_t)(kt * 32 + ty + i * 8) * V_ + vt * 32 + tx];
        __syncthreads();
#pragma unroll
        for (int i = 0; i < 4; i++)
            W2t[(size_t)(vt * 32 + ty + i * 8) * D_ + kt * 32 + tx] = tile[tx][ty + i * 8];
    }
}

// ---------------------------------------------------------------------------
// Kernel 2 (fused): C = tanh(encp'[bt] + decp[drw]) @ W2t^T + b2.
//
// ROUND-13: r6-champion structure with the tanh-duplication HALVED and the
// r11 spill avoided.
//   BM=64, BN=512 (dup x2 instead of x4), BK=32, 256 thr = 4 waves,
//   wave out = 64x128, accT[8][4] = 128 VGPR (swapped-operand).
//   __launch_bounds__(256,2): 2 waves/EU min -> 256-reg cap (~210 used,
//   NO spill — r11's fiasco was (512,2)'s 128-reg cap vs a 190-reg body).
//   LDS: A dbuf 2x4KB @0 + B dbuf 2x32KB @8192 = 72KB -> 2 blocks/CU.
// r5-proven single-__syncthreads-per-tile loop (best fused structure
// measured). B-restage total unchanged vs r5/r6 (1.02 GB). VALU pole
// (r6's largest: ~122k cyc/CU) halves to ~65k.
// 64B LDS rows -> r9-VERIFIED 2-bit involution slot16 ^= (row>>1)&3 on all
// paths; each reduces to a lane constant:
//   B g2l src:  (tid&3) ^ ((tid>>3)&3)   [row = tid>>2 + c*64; c*64 drops]
//   A write:    kq ^ ((pr>>1)&3)
//   frag read:  lk ^ ((lr>>1)&3)         [i*16/j*16/w*128 drop mod 4]
// Swapped-operand MFMA + dwordx4 epilogue (r9/r11-verified mapping).
// Accumulation order k-ascending, unchanged -> same absmax.
// ---------------------------------------------------------------------------
__global__ __launch_bounds__(256, 2) void joint_kernel(
    const float* __restrict__ encp, const float* __restrict__ decp,
    const __bf16* __restrict__ W2t, const float* __restrict__ b2,
    float* __restrict__ C) {
    __shared__ __align__(128) char lds[73728];   // A: 2x4KB @0, B: 2x32KB @8192

    const int bid = blockIdx.x;
    const int swz = (bid & 7) * 200 + (bid >> 3);   // 1600 = 8 XCD x 200
    const int mt = swz >> 1, nt = swz & 1;          // 800 M-tiles x 2 N-tiles
    const int m0 = mt * 64, n0 = nt * 512;

    const int tid = threadIdx.x;                    // 0..255
    const int w = tid >> 6, l = tid & 63;           // 4 waves; wave = N-col w
    const int lr = l & 15, lk = l >> 4;

    char* ldsp = (char*)lds;
    char* ldsB = ldsp + 8192;

    // ---- B staging: 8 g2l16/thread/tile; source slot pre-swizzled.
    const char* WbL = (const char*)W2t
        + (size_t)(n0 + (tid >> 2)) * 1280
        + (unsigned)((((tid & 3) ^ ((tid >> 3) & 3)) * 16));
    const unsigned bdst = (unsigned)tid * 16u;

    // ---- A produce: thread owns row pr (0..63), 8 k-elems at kq*8.
    const int pr = tid >> 2;
    const int kq = tid & 3;
    const int R  = m0 + pr;
    const int bt = R / 80;
    const int uu = R - bt * 80;
    const int drw = (bt / 160) * 80 + uu;
    const float* ep = encp + (size_t)bt * D_ + kq * 8;   // b1 already folded
    const float* dp = decp + (size_t)drw * D_ + kq * 8;
    const unsigned pw = (unsigned)(pr * 64 + ((kq ^ ((pr >> 1) & 3)) * 16));

    // ---- frag reads: phys slot = lk ^ ((lr>>1)&3).
    const unsigned px16 = (unsigned)((lk ^ ((lr >> 1) & 3)) * 16);

    // accT[j][i]: j = N sub-tile (8), i = M sub-tile (4) — swapped-operand.
    floatx4 accT[8][4] = {};

#define STAGE_B(BUF, T) do { \
    const char* _s = WbL + (size_t)(T) * 64; \
    char* _d = ldsB + (BUF) * 32768 + bdst; \
    _Pragma("unroll") for (int c = 0; c < 8; ++c) \
        g2l16(_s + (size_t)c * 81920, _d + c * 4096); \
  } while (0)

#define LOAD_ED(T) do { \
    const float* _e = ep + (T) * 32; const float* _d = dp + (T) * 32; \
    e0 = *(const floatx4*)_e;       e1 = *(const floatx4*)(_e + 4); \
    d0 = *(const floatx4*)_d;       d1 = *(const floatx4*)(_d + 4); \
  } while (0)

#define PRODUCE_A(BUF) do { \
    bf16x8 h; \
    _Pragma("unroll") for (int i2 = 0; i2 < 4; ++i2) { \
      h[i2]     = (__bf16)fast_tanh(e0[i2] + d0[i2]); \
      h[i2 + 4] = (__bf16)fast_tanh(e1[i2] + d1[i2]); \
    } \
    *(bf16x8*)(ldsp + (BUF) * 4096 + pw) = h; \
  } while (0)

#define FRAGS_MFMA(BUF) do { \
    bf16x8 af[4], bfr[8]; \
    _Pragma("unroll") for (int i = 0; i < 4; ++i) \
        af[i] = *(const bf16x8*)(ldsp + (BUF) * 4096 + (i * 16 + lr) * 64 + px16); \
    _Pragma("unroll") for (int j = 0; j < 8; ++j) \
        bfr[j] = *(const bf16x8*)(ldsB + (BUF) * 32768 + (w * 128 + j * 16 + lr) * 64 + px16); \
    _Pragma("unroll") for (int j = 0; j < 8; ++j) \
        _Pragma("unroll") for (int i = 0; i < 4; ++i) \
            accT[j][i] = __builtin_amdgcn_mfma_f32_16x16x32_bf16(bfr[j], af[i], accT[j][i], 0, 0, 0); \
  } while (0)

    // ---- prologue: tile 0 ----
    {
        floatx4 e0, e1, d0, d1;
        STAGE_B(0, 0);
        LOAD_ED(0);
        PRODUCE_A(0);
    }
    __syncthreads();

#pragma unroll 1
    for (int t = 0; t < 20; ++t) {                 // 20 K-tiles of 32
        const int buf = t & 1, nb = buf ^ 1;
        floatx4 e0, e1, d0, d1;
        if (t < 19) {
            STAGE_B(nb, t + 1);
            LOAD_ED(t + 1);
        }
        FRAGS_MFMA(buf);
        if (t < 19) PRODUCE_A(nb);
        __syncthreads();
    }

    // ---- epilogue (swapped layout, r9/r11-verified): lane&15 = M-row,
    // (lane>>4)*4 + reg = N-col -> 4 regs = 4 consecutive C columns.
#pragma unroll
    for (int j = 0; j < 8; ++j) {
        const int col0 = n0 + w * 128 + j * 16 + lk * 4;
        const floatx4 bv = *(const floatx4*)&b2[col0];
#pragma unroll
        for (int i = 0; i < 4; ++i) {
            const int row = m0 + i * 16 + lr;
            floatx4 v = { accT[j][i][0] + bv[0], accT[j][i][1] + bv[1],
                          accT[j][i][2] + bv[2], accT[j][i][3] + bv[3] };
            *(floatx4*)&C[(size_t)row * V_ + col0] = v;
        }
    }
#undef STAGE_B
#undef LOAD_ED
#undef PRODUCE_A
#undef FRAGS_MFMA
}

// ---------------------------------------------------------------------------
extern "C" void kernel_launch(void* const* d_in, const int* in_sizes, int n_in,
                              void* d_out, int out_size, void* d_ws, size_t ws_size,
                              hipStream_t stream) {
    const float* enc = (const float*)d_in[0];
    const float* dec = (const float*)d_in[1];
    const float* W1  = (const float*)d_in[2];
    const float* b1  = (const float*)d_in[3];
    const float* W2  = (const float*)d_in[4];
    const float* b2  = (const float*)d_in[5];
    float* out = (float*)d_out;

    // Workspace (d_ws), 3.77 MB:
    char* ws = (char*)d_ws;
    float*  encp = (float*)ws;                         // 640*640*4 (b1 folded)
    float*  decp = (float*)(ws + 1638400);             // 320*640*4
    __bf16* W2t  = (__bf16*)(ws + 1638400 + 819200);   // 1024*640*2

    prep_kernel<<<790, 256, 0, stream>>>(enc, dec, W1, b1, W2, encp, decp, W2t);
    joint_kernel<<<1600, 256, 0, stream>>>(encp, decp, W2t, b2, out);
}

// Round 14
// 331.934 us; speedup vs baseline: 1.1892x; 1.0232x over previous
//
#include <hip/hip_runtime.h>
#include <hip/hip_bf16.h>
#include <cstdint>

// Problem shape (Transducer joint network):
//   enc (4,160,640) fp32, dec (4,80,640) fp32, W1 (1280,640), b1 (640),
//   W2 (640,1024), b2 (1024).  out = (4,160,80,1024) fp32 = 52.4M floats.
#define D_    640
#define V_    1024
#define M_    51200

typedef __bf16 bf16x8 __attribute__((ext_vector_type(8)));
typedef float floatx4 __attribute__((ext_vector_type(4)));

__device__ __forceinline__ void g2l16(const void* g, void* l) {
    __builtin_amdgcn_global_load_lds((const __attribute__((address_space(1))) void*)g,
                                     (__attribute__((address_space(3))) void*)l,
                                     16, 0, 0);
}

__device__ __forceinline__ float fast_tanh(float x) {
    float e = __builtin_amdgcn_exp2f(x * 2.8853900817779268f); // 2*log2(e)
    return 1.0f - 2.0f * __builtin_amdgcn_rcpf(e + 1.0f);
}

// ---------------------------------------------------------------------------
// Kernel 1: fp32 projections -> d_ws. 64x64 tiles, 4x4/thread.
// b1 is FOLDED into encp here (k-only bias): hidden = tanh((e+b1) + d).
// ---------------------------------------------------------------------------
__global__ __launch_bounds__(256) void proj_kernel(
    const float* __restrict__ enc, const float* __restrict__ dec,
    const float* __restrict__ W1, const float* __restrict__ b1,
    float* __restrict__ encp, float* __restrict__ decp) {
    __shared__ float As[64][36];
    __shared__ float Ws[32][68];

    const int rt = blockIdx.y;     // 0..14 (10 enc row-tiles, 5 dec row-tiles)
    const int ct = blockIdx.x;     // 0..9
    const bool is_enc = (rt < 10);
    const float* Asrc; const float* Wsrc; float* Cdst;
    if (is_enc) { Asrc = enc + (size_t)rt * 64 * D_;        Wsrc = W1;           Cdst = encp + (size_t)rt * 64 * D_; }
    else        { Asrc = dec + (size_t)(rt - 10) * 64 * D_; Wsrc = W1 + D_ * D_; Cdst = decp + (size_t)(rt - 10) * 64 * D_; }

    const int tid = threadIdx.x;
    const int ar = tid >> 2,  ac = (tid & 3) * 8;
    const int wr2 = tid >> 3, wc2 = (tid & 7) * 8;
    const int tr = tid >> 4,  tc = tid & 15;

    float acc[4][4] = {};
    for (int k0 = 0; k0 < D_; k0 += 32) {
        __syncthreads();
        *(floatx4*)&As[ar][ac]       = *(const floatx4*)&Asrc[(size_t)ar * D_ + k0 + ac];
        *(floatx4*)&As[ar][ac + 4]   = *(const floatx4*)&Asrc[(size_t)ar * D_ + k0 + ac + 4];
        *(floatx4*)&Ws[wr2][wc2]     = *(const floatx4*)&Wsrc[(size_t)(k0 + wr2) * D_ + ct * 64 + wc2];
        *(floatx4*)&Ws[wr2][wc2 + 4] = *(const floatx4*)&Wsrc[(size_t)(k0 + wr2) * D_ + ct * 64 + wc2 + 4];
        __syncthreads();
#pragma unroll
        for (int kk = 0; kk < 32; kk++) {
            floatx4 w = *(const floatx4*)&Ws[kk][tc * 4];
            float a0 = As[tr * 4 + 0][kk], a1 = As[tr * 4 + 1][kk];
            float a2 = As[tr * 4 + 2][kk], a3 = As[tr * 4 + 3][kk];
#pragma unroll
            for (int j = 0; j < 4; j++) {
                acc[0][j] += a0 * w[j]; acc[1][j] += a1 * w[j];
                acc[2][j] += a2 * w[j]; acc[3][j] += a3 * w[j];
            }
        }
    }
    floatx4 bv = {0.f, 0.f, 0.f, 0.f};
    if (is_enc) bv = *(const floatx4*)&b1[ct * 64 + tc * 4];
#pragma unroll
    for (int i = 0; i < 4; i++) {
        floatx4 v = { acc[i][0] + bv[0], acc[i][1] + bv[1],
                      acc[i][2] + bv[2], acc[i][3] + bv[3] };
        *(floatx4*)&Cdst[(size_t)(tr * 4 + i) * D_ + ct * 64 + tc * 4] = v;
    }
}

// ---------------------------------------------------------------------------
// Kernel 2: W2 (640x1024 fp32 KxN) -> W2t (1024x640 bf16 NxK) in d_ws.
// ---------------------------------------------------------------------------
__global__ __launch_bounds__(256) void w2t_kernel(
    const float* __restrict__ W2, __bf16* __restrict__ W2t) {
    __shared__ __bf16 tile[32][33];
    const int vt = blockIdx.x;           // 0..31
    const int kt = blockIdx.y;           // 0..19
    const int tx = threadIdx.x & 31, ty = threadIdx.x >> 5;
#pragma unroll
    for (int i = 0; i < 4; i++)
        tile[ty + i * 8][tx] = (__bf16)W2[(size_t)(kt * 32 + ty + i * 8) * V_ + vt * 32 + tx];
    __syncthreads();
#pragma unroll
    for (int i = 0; i < 4; i++)
        W2t[(size_t)(vt * 32 + ty + i * 8) * D_ + kt * 32 + tx] = tile[tx][ty + i * 8];
}

// ---------------------------------------------------------------------------
// Kernel 3 (fused): C = tanh(encp'[bt] + decp[drw]) @ W2t^T + b2.
// BM=64, BN=256, BK=64, 256 thr = 4 waves (1M x 4N), wave out = 64x64.
// LDS 80KB -> 2 blocks/CU. Conflict-free slot^=(row&7) swizzle (r5: 0 conf).
//
// T4 counted-vmcnt pipeline:
//   per iter t: STAGE_B(t+1) [8 vmem, pinned FIRST] ; LOAD_ED(t+2) -> regs ;
//   frags+MFMA(t) ; PRODUCE_A(t+1) from regs loaded LAST iter ;
//   s_waitcnt vmcnt(8) lgkmcnt(0) ; raw s_barrier.
// The 8 ED(t+2) loads stay in flight ACROSS the barrier; only B(t+1) (the
// oldest 8) must land. t=8 has no ED issue -> vmcnt(0). t=9 peeled.
// sched_barrier(0) pins STAGE_B-before-LOAD_ED (the counting assumption)
// and fences the waitcnt/barrier pair (guide rule #18).
//
// This configuration is the session champion (330.9 us harness-verified);
// locked in after r7-r13 structural experiments (bigger BM, reg-direct B,
// separate-H + 8-phase 256^2 gemm, full-N fusion, BN=512) all measured
// equal-or-worse: the kernel is convoy/serialization-bound at ~140 us and
// every pipe sits at ~20% — no single-pole fix applies at HIP source level.
// ---------------------------------------------------------------------------
#define SCB  __builtin_amdgcn_sched_barrier(0)

__global__ __launch_bounds__(256, 2) void joint_kernel(
    const float* __restrict__ encp, const float* __restrict__ decp,
    const __bf16* __restrict__ W2t, const float* __restrict__ b2,
    float* __restrict__ C) {
    __shared__ __align__(128) char lds[81920];   // A: 2x8KB @0, B: 2x32KB @16384

    const int bid = blockIdx.x;
    const int swz = (bid & 7) * 400 + (bid >> 3);   // 3200 = 8 XCD x 400
    const int mt = swz >> 2, nt = swz & 3;          // 800 M-tiles x 4 N-tiles
    const int m0 = mt * 64, n0 = nt * 256;

    const int tid = threadIdx.x;                    // 0..255
    const int w = tid >> 6, l = tid & 63;           // 4 waves; wave = N-col w
    const int lr = l & 15, lk = l >> 4;

    char* ldsp = (char*)lds;

    // ---- B staging: 8 g2l16/thread/tile; source column pre-swizzled so the
    // linear LDS dest yields lds[row][slot] = W2t[row][slot ^ (row&7)].
    const char* Wb = (const char*)W2t
        + (size_t)(n0 + (tid >> 3)) * 1280
        + (unsigned)((((tid & 7) ^ ((tid >> 3) & 7)) * 16));
    const unsigned bdst = 16384u + (unsigned)tid * 16u;

    // ---- A produce: thread owns row pr (0..63), k-quarter kq (16 elems).
    const int pr = tid >> 2;
    const int kq = tid & 3;
    const int R  = m0 + pr;
    const int bt = R / 80;
    const int uu = R - bt * 80;
    const int drw = (bt / 160) * 80 + uu;
    const float* ep = encp + (size_t)bt * D_ + kq * 16;   // b1 already folded in
    const float* dp = decp + (size_t)drw * D_ + kq * 16;
    const unsigned pw0 = (unsigned)(pr * 128 + (((kq * 2)     ^ (pr & 7)) * 16));
    const unsigned pw1 = (unsigned)(pr * 128 + (((kq * 2 + 1) ^ (pr & 7)) * 16));

    floatx4 acc[4][4] = {};

#define STAGE_B(BUF, T) do { \
    const char* _s = Wb + (size_t)(T) * 128; \
    char* _d = ldsp + bdst + (BUF) * 32768; \
    g2l16(_s,           _d); \
    g2l16(_s +  40960,  _d +  4096); \
    g2l16(_s +  81920,  _d +  8192); \
    g2l16(_s + 122880,  _d + 12288); \
    g2l16(_s + 163840,  _d + 16384); \
    g2l16(_s + 204800,  _d + 20480); \
    g2l16(_s + 245760,  _d + 24576); \
    g2l16(_s + 286720,  _d + 28672); \
  } while (0)

#define LOAD_ED2(T, EV, DV) do { \
    const float* _e = ep + (T) * 64; const float* _d = dp + (T) * 64; \
    _Pragma("unroll") for (int q = 0; q < 4; ++q) { \
      EV[q] = *(const floatx4*)(_e + q * 4); \
      DV[q] = *(const floatx4*)(_d + q * 4); \
    } } while (0)

#define PRODUCE_A2(BUF, EV, DV) do { \
    bf16x8 h0, h1; \
    _Pragma("unroll") for (int q = 0; q < 4; ++q) { \
      _Pragma("unroll") for (int i2 = 0; i2 < 4; ++i2) { \
        float t_ = fast_tanh(EV[q][i2] + DV[q][i2]); \
        if (q < 2) h0[q * 4 + i2] = (__bf16)t_; else h1[(q - 2) * 4 + i2] = (__bf16)t_; \
      } } \
    *(bf16x8*)(ldsp + (BUF) * 8192 + pw0) = h0; \
    *(bf16x8*)(ldsp + (BUF) * 8192 + pw1) = h1; \
  } while (0)

#define FRAGS_MFMA(BUF) do { \
    _Pragma("unroll") \
    for (int s = 0; s < 2; ++s) { \
        const unsigned sx = (unsigned)((((s * 4 + lk) ^ (lr & 7)) * 16)); \
        bf16x8 af[4], bfr[4]; \
        _Pragma("unroll") for (int i = 0; i < 4; ++i) \
            af[i] = *(const bf16x8*)(ldsp + (BUF) * 8192 + (i * 16 + lr) * 128 + sx); \
        _Pragma("unroll") for (int j = 0; j < 4; ++j) \
            bfr[j] = *(const bf16x8*)(ldsp + 16384 + (BUF) * 32768 + (w * 64 + j * 16 + lr) * 128 + sx); \
        _Pragma("unroll") for (int i = 0; i < 4; ++i) \
            _Pragma("unroll") for (int j = 0; j < 4; ++j) \
                acc[i][j] = __builtin_amdgcn_mfma_f32_16x16x32_bf16(af[i], bfr[j], acc[i][j], 0, 0, 0); \
    } } while (0)

    floatx4 eC[4] = {}, dC[4] = {}, eN[4] = {}, dN[4] = {};

    // ---- prologue: tile 0 staged+produced; ED(1) left in flight (8) ----
    STAGE_B(0, 0);
    SCB;
    {
        floatx4 e0[4], d0[4];
        LOAD_ED2(0, e0, d0);
        LOAD_ED2(1, eC, dC);
        PRODUCE_A2(0, e0, d0);   // compiler wait for e0/d0 also drains B(0)
    }
    SCB;
    asm volatile("s_waitcnt vmcnt(8) lgkmcnt(0)" ::: "memory");
    __builtin_amdgcn_s_barrier();
    SCB;

#pragma unroll 1
    for (int t = 0; t < 9; ++t) {
        const int buf = t & 1, nb = buf ^ 1;
        STAGE_B(nb, t + 1);            // oldest 8 vmem this iter (pinned)
        SCB;
        if (t < 8) LOAD_ED2(t + 2, eN, dN);   // 8 newer vmem, span barrier
        FRAGS_MFMA(buf);
        PRODUCE_A2(nb, eC, dC);        // uses ED(t+1) from last iter
#pragma unroll
        for (int q = 0; q < 4; ++q) { eC[q] = eN[q]; dC[q] = dN[q]; }
        SCB;
        if (t == 8) { asm volatile("s_waitcnt vmcnt(0) lgkmcnt(0)" ::: "memory"); }
        else        { asm volatile("s_waitcnt vmcnt(8) lgkmcnt(0)" ::: "memory"); }
        __builtin_amdgcn_s_barrier();
        SCB;
    }
    // ---- t = 9 (peeled): compute only ----
    FRAGS_MFMA(1);

    // ---- epilogue: C/D layout col = lane&15 (N), row = (lane>>4)*4+reg (M) ----
#pragma unroll
    for (int j = 0; j < 4; ++j) {
        const int col = n0 + w * 64 + j * 16 + lr;
        const float bj = b2[col];
#pragma unroll
        for (int i = 0; i < 4; ++i) {
            const int row = m0 + i * 16 + lk * 4;
            float* Cp = C + (size_t)row * V_ + col;
#pragma unroll
            for (int rg = 0; rg < 4; ++rg)
                Cp[(size_t)rg * V_] = acc[i][j][rg] + bj;
        }
    }
#undef STAGE_B
#undef LOAD_ED2
#undef PRODUCE_A2
#undef FRAGS_MFMA
}

// ---------------------------------------------------------------------------
extern "C" void kernel_launch(void* const* d_in, const int* in_sizes, int n_in,
                              void* d_out, int out_size, void* d_ws, size_t ws_size,
                              hipStream_t stream) {
    const float* enc = (const float*)d_in[0];
    const float* dec = (const float*)d_in[1];
    const float* W1  = (const float*)d_in[2];
    const float* b1  = (const float*)d_in[3];
    const float* W2  = (const float*)d_in[4];
    const float* b2  = (const float*)d_in[5];
    float* out = (float*)d_out;

    // Workspace (d_ws):
    char* ws = (char*)d_ws;
    float*  encp = (float*)ws;                         // 640*640*4  = 1,638,400 (b1 folded)
    float*  decp = (float*)(ws + 1638400);             // 320*640*4  =   819,200
    __bf16* W2t  = (__bf16*)(ws + 1638400 + 819200);   // 1024*640*2 = 1,310,720

    proj_kernel<<<dim3(10, 15), 256, 0, stream>>>(enc, dec, W1, b1, encp, decp);
    w2t_kernel<<<dim3(32, 20), 256, 0, stream>>>(W2, W2t);
    joint_kernel<<<3200, 256, 0, stream>>>(encp, decp, W2t, b2, out);
}